// Round 7
// baseline (511.742 us; speedup 1.0000x reference)
//
#include <hip/hip_runtime.h>
#include <hip/hip_bf16.h>
#include <hip/hip_fp16.h>
#include <cstdint>

typedef _Float16 f16;
typedef _Float16 f16x8 __attribute__((ext_vector_type(8)));
typedef _Float16 f16x4 __attribute__((ext_vector_type(4)));
typedef float f32x4 __attribute__((ext_vector_type(4)));

#define DEV_INLINE __device__ __forceinline__

// async 16B/lane global->LDS. LDS dest is wave-uniform base + lane*16.
DEV_INLINE void async_ld16(const void* g, void* l) {
  __builtin_amdgcn_global_load_lds((const __attribute__((address_space(1))) void*)g,
                                   (__attribute__((address_space(3))) void*)l, 16, 0, 0);
}

template <int N>
DEV_INLINE void wait_vm() {
  static_assert(N >= 0 && N <= 12, "gate range");
  if constexpr (N == 0)  asm volatile("s_waitcnt vmcnt(0)" ::: "memory");
  if constexpr (N == 1)  asm volatile("s_waitcnt vmcnt(1)" ::: "memory");
  if constexpr (N == 2)  asm volatile("s_waitcnt vmcnt(2)" ::: "memory");
  if constexpr (N == 3)  asm volatile("s_waitcnt vmcnt(3)" ::: "memory");
  if constexpr (N == 4)  asm volatile("s_waitcnt vmcnt(4)" ::: "memory");
  if constexpr (N == 5)  asm volatile("s_waitcnt vmcnt(5)" ::: "memory");
  if constexpr (N == 6)  asm volatile("s_waitcnt vmcnt(6)" ::: "memory");
  if constexpr (N == 7)  asm volatile("s_waitcnt vmcnt(7)" ::: "memory");
  if constexpr (N == 8)  asm volatile("s_waitcnt vmcnt(8)" ::: "memory");
  if constexpr (N == 9)  asm volatile("s_waitcnt vmcnt(9)" ::: "memory");
  if constexpr (N == 10) asm volatile("s_waitcnt vmcnt(10)" ::: "memory");
  if constexpr (N == 11) asm volatile("s_waitcnt vmcnt(11)" ::: "memory");
  if constexpr (N == 12) asm volatile("s_waitcnt vmcnt(12)" ::: "memory");
}
DEV_INLINE void lgk0() {
  asm volatile("s_waitcnt lgkmcnt(0)" ::: "memory");
  __builtin_amdgcn_sched_barrier(0);
}

// ---------------- elementwise prep kernels ----------------

// x f32 [2048][4096] -> Acat f16 [2048][8192] = [hi(4096) | lo(4096)]
__global__ __launch_bounds__(256) void k_cast_x_split(const float* __restrict__ x,
                                                      f16* __restrict__ acat) {
  int idx = blockIdx.x * 256 + threadIdx.x;
  int i = idx * 4;
  if (i >= 2048 * 4096) return;
  float4 v = *(const float4*)&x[i];
  int row = i >> 12, col = i & 4095;
  f16 h0 = (f16)v.x, h1 = (f16)v.y, h2 = (f16)v.z, h3 = (f16)v.w;
  f16x4 hi = {h0, h1, h2, h3};
  f16x4 lo = {(f16)(v.x - (float)h0), (f16)(v.y - (float)h1),
              (f16)(v.z - (float)h2), (f16)(v.w - (float)h3)};
  size_t base = (size_t)row * 8192 + col;
  *(f16x4*)&acat[base] = hi;
  *(f16x4*)&acat[base + 4096] = lo;
}

// int32 weights (values in [-127,127], exact in f16) -> f16
__global__ __launch_bounds__(256) void k_cast_i32_f16(const int* __restrict__ w,
                                                      f16* __restrict__ out, int n) {
  int i = (blockIdx.x * 256 + threadIdx.x) * 4;
  if (i >= n) return;
  int4 v = *(const int4*)&w[i];
  f16x4 o = {(f16)(float)v.x, (f16)(float)v.y, (f16)(float)v.z, (f16)(float)v.w};
  *(f16x4*)&out[i] = o;
}

// merged: wq|wk|wv -> Wcat f16 [6144][4096] + bias/scale vectors
__global__ __launch_bounds__(256) void k_prep_w(
    const int* __restrict__ wq, const int* __restrict__ wk, const int* __restrict__ wv,
    const float* __restrict__ bq, const float* __restrict__ bk, const float* __restrict__ bv,
    const float* __restrict__ sq, const float* __restrict__ sk, const float* __restrict__ sv,
    f16* __restrict__ wcat, float* __restrict__ bias_cat, float* __restrict__ scale_cat) {
  int i = blockIdx.x * 256 + threadIdx.x;
  if (i < 6291456) {
    int e = i * 4, row = e >> 12, col = e & 4095;
    int4 v;
    if (row < 4096)      v = *(const int4*)&wq[(size_t)row * 4096 + col];
    else if (row < 5120) v = *(const int4*)&wk[(size_t)(row - 4096) * 4096 + col];
    else                 v = *(const int4*)&wv[(size_t)(row - 5120) * 4096 + col];
    f16x4 o = {(f16)(float)v.x, (f16)(float)v.y, (f16)(float)v.z, (f16)(float)v.w};
    *(f16x4*)&wcat[e] = o;
  }
  if (i < 6144) {
    float b, s;
    if (i < 4096)      { b = bq[i];        s = sq[0]; }
    else if (i < 5120) { b = bk[i - 4096]; s = sk[0]; }
    else               { b = bv[i - 5120]; s = sv[0]; }
    bias_cat[i] = b;
    scale_cat[i] = s;
  }
}

// ---------------- GEMM v6: 8-wave exact-fill, 4-phase, gate->barrier->read ----------------
// (unchanged from round 6 — 925 TF, 0 bank conflicts, race-free invariant)
template <int BM, int BN, int MODE>
__global__ __launch_bounds__(512) void k_gemm6(
    const f16* __restrict__ A, const f16* __restrict__ W,
    f16* __restrict__ o_hi, f16* __restrict__ o_lo, float* __restrict__ o_f32,
    const float* __restrict__ scale_vec, const float* __restrict__ bias_vec,
    const float* __restrict__ scale_scalar,
    int N, int K, int kmask, int ldw, int nym) {
  constexpr int WM = 2, WN = 4;
  constexpr int MR = BM / WM / 16;
  constexpr int NR = BN / WN / 16;
  constexpr int NH = NR / 2;
  constexpr int AKC = BM * 64;
  constexpr int BKC = BN * 64;
  constexpr int SLOT = 2 * (AKC + BKC);
  constexpr int LAH = AKC / 8192;
  constexpr int LBH = BKC / 8192;
  constexpr int GS = 2 * LBH + 3;
  constexpr int GT1 = 2 * LBH + 2;
  constexpr int GT2 = LBH + 1;
  extern __shared__ __align__(16) char lds[];

  const int t = threadIdx.x, w = t >> 6, ln = t & 63;
  const int lr = ln & 15, lg = ln >> 4;
  const int wn = w & 3, wm = w >> 2;

  const int nwg = gridDim.x;
  const int q8 = nwg >> 3, r8 = nwg & 7;
  const int xcd = blockIdx.x & 7, bidx = blockIdx.x >> 3;
  const int sid = (xcd < r8 ? xcd * (q8 + 1) : r8 * (q8 + 1) + (xcd - r8) * q8) + bidx;
  const int m0 = (sid % nym) * BM;
  const int n0 = (sid / nym) * BN;

  const f16* aSrc[LAH];
  const f16* bSrc[LBH];
#pragma unroll
  for (int l = 0; l < LAH; l++) {
    int ci = l * 512 + t, row = ci >> 2, c = ci & 3;
    aSrc[l] = A + (size_t)(m0 + row) * K + (c ^ ((row >> 1) & 3)) * 8;
  }
#pragma unroll
  for (int l = 0; l < LBH; l++) {
    int ci = l * 512 + t, row = ci >> 2, c = ci & 3;
    bSrc[l] = W + (size_t)(n0 + row) * ldw + (c ^ ((row >> 1) & 3)) * 8;
  }

  f32x4 acc[MR][NR] = {};
  f16x8 af[MR], bflo[NH], bfhi[NH];

  auto stageA = [&](int tt, int kc) {
    char* dst = lds + (tt & 1) * SLOT + kc * AKC;
    const int ko = tt * 64 + kc * 32;
#pragma unroll
    for (int l = 0; l < LAH; l++)
      async_ld16(aSrc[l] + ko, dst + (l * 512 + w * 64) * 16);
  };
  auto stageB = [&](int tt, int kc) {
    char* dst = lds + (tt & 1) * SLOT + 2 * AKC + kc * BKC;
    const int ko = ((tt * 64) & kmask) + kc * 32;
#pragma unroll
    for (int l = 0; l < LBH; l++)
      async_ld16(bSrc[l] + ko, dst + (l * 512 + w * 64) * 16);
  };
  auto readA = [&](int tt, int kc) {
    const char* base = lds + (tt & 1) * SLOT + kc * AKC;
#pragma unroll
    for (int mf = 0; mf < MR; mf++) {
      const int row = wm * (BM / WM) + mf * 16 + lr;
      af[mf] = *(const f16x8*)(base + row * 64 + (lg ^ ((row >> 1) & 3)) * 16);
    }
  };
  auto readB = [&](f16x8 (&dst)[NH], int tt, int nq, int kc) {
    const char* base = lds + (tt & 1) * SLOT + 2 * AKC + kc * BKC;
#pragma unroll
    for (int nf = 0; nf < NH; nf++) {
      const int row = wn * (BN / WN) + (nq * NH + nf) * 16 + lr;
      dst[nf] = *(const f16x8*)(base + row * 64 + (lg ^ ((row >> 1) & 3)) * 16);
    }
  };
  auto mma = [&](f16x8 (&b)[NH], int nq) {
    __builtin_amdgcn_s_setprio(1);
#pragma unroll
    for (int m = 0; m < MR; m++)
#pragma unroll
      for (int n = 0; n < NH; n++)
        acc[m][nq * NH + n] =
            __builtin_amdgcn_mfma_f32_16x16x32_f16(af[m], b[n], acc[m][nq * NH + n], 0, 0, 0);
    __builtin_amdgcn_s_setprio(0);
  };
  auto bar = [&]() { __builtin_amdgcn_s_barrier(); };

  const int NT = K >> 6;
  stageA(0, 0); stageB(0, 0); stageA(0, 1); stageB(0, 1);
  stageA(1, 0); stageB(1, 0); stageA(1, 1);
  wait_vm<GS>();
  bar();

  for (int tt = 0; tt + 2 < NT; ++tt) {
    stageB(tt + 1, 1);
    readA(tt, 0); readB(bflo, tt, 0, 0);
    bar(); lgk0(); mma(bflo, 0); bar();
    stageA(tt + 2, 0);
    readB(bfhi, tt, 1, 0);
    wait_vm<GS>();
    bar(); lgk0(); mma(bfhi, 1); bar();
    stageB(tt + 2, 0);
    readA(tt, 1); readB(bflo, tt, 0, 1);
    bar(); lgk0(); mma(bflo, 0); bar();
    stageA(tt + 2, 1);
    readB(bfhi, tt, 1, 1);
    wait_vm<GS>();
    bar(); lgk0(); mma(bfhi, 1); bar();
  }
  {
    const int tt = NT - 2;
    stageB(tt + 1, 1);
    readA(tt, 0); readB(bflo, tt, 0, 0);
    bar(); lgk0(); mma(bflo, 0); bar();
    readB(bfhi, tt, 1, 0);
    wait_vm<GT1>();
    bar(); lgk0(); mma(bfhi, 1); bar();
    readA(tt, 1); readB(bflo, tt, 0, 1);
    bar(); lgk0(); mma(bflo, 0); bar();
    readB(bfhi, tt, 1, 1);
    wait_vm<GT2>();
    bar(); lgk0(); mma(bfhi, 1); bar();
  }
  {
    const int tt = NT - 1;
    readA(tt, 0); readB(bflo, tt, 0, 0);
    bar(); lgk0(); mma(bflo, 0); bar();
    readB(bfhi, tt, 1, 0);
    wait_vm<0>();
    bar(); lgk0(); mma(bfhi, 1); bar();
    readA(tt, 1); readB(bflo, tt, 0, 1);
    bar(); lgk0(); mma(bflo, 0); bar();
    readB(bfhi, tt, 1, 1);
    bar(); lgk0(); mma(bfhi, 1);
  }

#pragma unroll
  for (int n = 0; n < NR; n++) {
    const int col = n0 + wn * (BN / WN) + n * 16 + lr;
    const float sc = (MODE == 0) ? scale_vec[col] : scale_scalar[0];
    const float bs = (MODE == 0) ? bias_vec[col] : 0.f;
#pragma unroll
    for (int m = 0; m < MR; m++)
#pragma unroll
      for (int r2 = 0; r2 < 4; r2++) {
        const int row = m0 + wm * (BM / WM) + m * 16 + lg * 4 + r2;
        const float v = acc[m][n][r2] * sc + bs;
        if constexpr (MODE == 0) {
          f16 h = (f16)v;
          o_hi[(size_t)row * N + col] = h;
          o_lo[(size_t)row * N + col] = (f16)(v - (float)h);
        } else {
          o_f32[(size_t)row * N + col] = v;
        }
      }
  }
}

// ---------------- RoPE on split Q/K (cols 0..5119 of 6144), f32 math ----------------
__global__ __launch_bounds__(256) void k_rope(f16* __restrict__ XH, f16* __restrict__ XL,
                                              const float* __restrict__ cosT,
                                              const float* __restrict__ sinT,
                                              const int* __restrict__ sp) {
  int idx = blockIdx.x * 256 + threadIdx.x;  // 2048 tokens * 40 heads * 64 pairs
  if (idx >= 2048 * 40 * 64) return;
  int p = idx & 63;
  int hh = (idx >> 6) % 40;
  int tkn = idx / (40 * 64);
  int col = (hh < 32) ? hh * 128 + p : 4096 + (hh - 32) * 128 + p;
  size_t i1 = (size_t)tkn * 6144 + col, i2 = i1 + 64;
  float x1 = (float)XH[i1] + (float)XL[i1];
  float x2 = (float)XH[i2] + (float)XL[i2];
  int pos = (tkn & 1023) + sp[0];
  float c = cosT[pos * 128 + p], s = sinT[pos * 128 + p];
  float o1 = x1 * c - x2 * s;
  float o2 = x2 * c + x1 * s;
  f16 h1 = (f16)o1, h2 = (f16)o2;
  XH[i1] = h1; XL[i1] = (f16)(o1 - (float)h1);
  XH[i2] = h2; XL[i2] = (f16)(o2 - (float)h2);
}

// ---------------- flash attention v2: pipelined staging, causal, GQA 4:1 ----------------
// 4 waves, 64 q-rows/block (16/wave), KVBLK=32 double-buffered.
// K hi/lo: global_load_lds into linear [32][128] with XOR swizzle (granule ^= row&7)
//   applied to the GLOBAL source (linear dest, m173) and to ds_read addr.
// V: global->reg prefetch during compute; transposed ds_write into dbuf VT after
//   barrier (T14 async split). Drain: vmcnt(0) AFTER compute -> barrier -> writeVT
//   -> lgkmcnt(0) -> barrier (gate->barrier->read invariant everywhere).
__global__ __launch_bounds__(256) void k_attn2(const f16* __restrict__ XH,
                                               const f16* __restrict__ XL,
                                               f16* __restrict__ out) {
  __shared__ __align__(16) f16 KsH[2][32 * 128];
  __shared__ __align__(16) f16 KsL[2][32 * 128];
  __shared__ __align__(16) f16 VT[2][128 * 40];
  __shared__ __align__(16) f16 Pb[4 * 16 * 40];
  const int t = threadIdx.x, w = t >> 6, l = t & 63;
  const int lr = l & 15, lg = l >> 4;
  const int qb = blockIdx.x, h = blockIdx.y, b = blockIdx.z;
  const int q0 = qb * 64, kvh = h >> 2;
  const size_t rs_ = 6144;
  const f16* Qh = XH + ((size_t)(b * 1024 + q0)) * rs_ + h * 128;
  const f16* Ql_ = XL + ((size_t)(b * 1024 + q0)) * rs_ + h * 128;
  const f16* KhG = XH + ((size_t)(b * 1024)) * rs_ + 4096 + kvh * 128;
  const f16* KlG = XL + ((size_t)(b * 1024)) * rs_ + 4096 + kvh * 128;
  const f16* VG = XH + ((size_t)(b * 1024)) * rs_ + 5120 + kvh * 128;

  f16x8 qh[4], ql[4];
  {
    size_t qoff = (size_t)(w * 16 + lr) * rs_ + lg * 8;
#pragma unroll
    for (int c = 0; c < 4; c++) {
      qh[c] = *(const f16x8*)(Qh + qoff + c * 32);
      ql[c] = *(const f16x8*)(Ql_ + qoff + c * 32);
    }
  }
  f32x4 accd[8] = {};
  float m_r[4], l_r[4];
#pragma unroll
  for (int r = 0; r < 4; r++) { m_r[r] = -1e30f; l_r[r] = 0.f; }

  f16x8 vreg[2];
  auto stageK = [&](int kv0, int buf) {
#pragma unroll
    for (int i = 0; i < 2; i++) {
      int ci = i * 256 + t, row = ci >> 4, ch = ci & 15;
      int chs = ch ^ (row & 7);  // XOR swizzle on global source
      size_t go = (size_t)(kv0 + row) * rs_ + chs * 8;
      char* dH = (char*)&KsH[buf][0] + (i * 256 + w * 64) * 16;
      char* dL = (char*)&KsL[buf][0] + (i * 256 + w * 64) * 16;
      async_ld16(KhG + go, dH);
      async_ld16(KlG + go, dL);
    }
  };
  auto loadV = [&](int kv0) {
#pragma unroll
    for (int i = 0; i < 2; i++) {
      int slot = i * 256 + t, row = slot & 31, d8 = slot >> 5;
      vreg[i] = *(const f16x8*)(VG + (size_t)(kv0 + row) * rs_ + d8 * 8);
    }
  };
  auto writeVT = [&](int buf) {
#pragma unroll
    for (int i = 0; i < 2; i++) {
      int slot = i * 256 + t, row = slot & 31, d8 = slot >> 5;
#pragma unroll
      for (int j = 0; j < 8; j++) VT[buf][(d8 * 8 + j) * 40 + row] = vreg[i][j];
    }
  };

  const int NT = (q0 + 64) >> 5;
  // prologue: tile 0 staged + drained; VT(0) built
  stageK(0, 0); loadV(0);
  wait_vm<0>();
  __builtin_amdgcn_s_barrier();
  writeVT(0);
  asm volatile("s_waitcnt lgkmcnt(0)" ::: "memory");
  __builtin_amdgcn_s_barrier();

  for (int tt = 0; tt < NT; ++tt) {
    const int cur = tt & 1;
    const int kv0 = tt * 32;
    const bool pf = (tt + 1 < NT);
    if (pf) { stageK(kv0 + 32, cur ^ 1); loadV(kv0 + 32); }  // in flight under compute

    // scores: S[q, k] over 16q x 32k, split 3-MFMA, swizzled K reads
    f32x4 sc[2] = {};
#pragma unroll
    for (int cb = 0; cb < 2; cb++) {
      const int krow = cb * 16 + lr;
#pragma unroll
      for (int c = 0; c < 4; c++) {
        const int gidx = ((c * 4 + lg) ^ (krow & 7)) * 8;
        const f16x8 kh = *(const f16x8*)&KsH[cur][krow * 128 + gidx];
        const f16x8 kl = *(const f16x8*)&KsL[cur][krow * 128 + gidx];
        sc[cb] = __builtin_amdgcn_mfma_f32_16x16x32_f16(qh[c], kh, sc[cb], 0, 0, 0);
        sc[cb] = __builtin_amdgcn_mfma_f32_16x16x32_f16(qh[c], kl, sc[cb], 0, 0, 0);
        sc[cb] = __builtin_amdgcn_mfma_f32_16x16x32_f16(ql[c], kh, sc[cb], 0, 0, 0);
      }
    }

    const float scale = 0.088388347648318447f;  // 1/sqrt(128)
    float alpha[4], pv[2][4];
#pragma unroll
    for (int r = 0; r < 4; r++) {
      const int qg = q0 + w * 16 + lg * 4 + r;
      float mx = -1e30f;
#pragma unroll
      for (int cb = 0; cb < 2; cb++) {
        const int kg = kv0 + cb * 16 + lr;
        float s = sc[cb][r] * scale;
        s = (kg <= qg) ? s : -1e30f;
        pv[cb][r] = s;
        mx = fmaxf(mx, s);
      }
      mx = fmaxf(mx, __shfl_xor(mx, 1));
      mx = fmaxf(mx, __shfl_xor(mx, 2));
      mx = fmaxf(mx, __shfl_xor(mx, 4));
      mx = fmaxf(mx, __shfl_xor(mx, 8));
      const float mn = fmaxf(m_r[r], mx);
      alpha[r] = __expf(m_r[r] - mn);
      m_r[r] = mn;
      float rsum = 0.f;
#pragma unroll
      for (int cb = 0; cb < 2; cb++) {
        const int kg = kv0 + cb * 16 + lr;
        const float p = (kg <= qg) ? __expf(pv[cb][r] - mn) : 0.f;
        pv[cb][r] = p;
        rsum += p;
      }
      rsum += __shfl_xor(rsum, 1);
      rsum += __shfl_xor(rsum, 2);
      rsum += __shfl_xor(rsum, 4);
      rsum += __shfl_xor(rsum, 8);
      l_r[r] = l_r[r] * alpha[r] + rsum;
    }

    // P (C-layout) -> per-wave LDS, then A-fragment read (wave-private, in-order DS)
    f16* Pw = &Pb[w * 16 * 40];
#pragma unroll
    for (int r = 0; r < 4; r++)
#pragma unroll
      for (int cb = 0; cb < 2; cb++)
        Pw[(lg * 4 + r) * 40 + cb * 16 + lr] = (f16)pv[cb][r];
    const f16x8 pf_ = *(const f16x8*)&Pw[lr * 40 + lg * 8];

#pragma unroll
    for (int dc = 0; dc < 8; dc++) {
      const f16x8 vf = *(const f16x8*)&VT[cur][(dc * 16 + lr) * 40 + lg * 8];
#pragma unroll
      for (int r = 0; r < 4; r++) accd[dc][r] *= alpha[r];
      accd[dc] = __builtin_amdgcn_mfma_f32_16x16x32_f16(pf_, vf, accd[dc], 0, 0, 0);
    }

    if (pf) {
      wait_vm<0>();                    // K(t+1) glds + V regs landed (hidden by compute)
      __builtin_amdgcn_s_barrier();    // all waves' K visible; VT[cur^1] readers done
      writeVT(cur ^ 1);
      asm volatile("s_waitcnt lgkmcnt(0)" ::: "memory");
      __builtin_amdgcn_s_barrier();    // VT(t+1) visible block-wide
    }
  }

#pragma unroll
  for (int dc = 0; dc < 8; dc++)
#pragma unroll
    for (int r = 0; r < 4; r++) {
      const int row = b * 1024 + q0 + w * 16 + lg * 4 + r;
      out[(size_t)row * 4096 + h * 128 + dc * 16 + lr] = (f16)(accd[dc][r] / l_r[r]);
    }
}

// ---------------- launch ----------------
extern "C" void kernel_launch(void* const* d_in, const int* in_sizes, int n_in,
                              void* d_out, int out_size, void* d_ws, size_t ws_size,
                              hipStream_t stream) {
  const float* x = (const float*)d_in[0];
  const float* cosT = (const float*)d_in[2];
  const float* sinT = (const float*)d_in[3];
  const int* wq = (const int*)d_in[4];
  const float* bq = (const float*)d_in[5];
  const float* sq = (const float*)d_in[6];
  const int* wk = (const int*)d_in[7];
  const float* bk = (const float*)d_in[8];
  const float* sk = (const float*)d_in[9];
  const int* wv = (const int*)d_in[10];
  const float* bv = (const float*)d_in[11];
  const float* sv = (const float*)d_in[12];
  const int* wo = (const int*)d_in[13];
  const float* so = (const float*)d_in[14];
  const int* sp = (const int*)d_in[15];

  char* ws = (char*)d_ws;
  f16* Acat = (f16*)ws;                        // x hi|lo [2048][8192]; later reused for Wo
  f16* Wcat = (f16*)(ws + 33554432);           // wq|wk|wv f16 [6144][4096]
  f16* XH = (f16*)(ws + 83886080);             // qkv hi [2048][6144]
  f16* XL = (f16*)(ws + 109051904);            // qkv lo
  f16* AO = (f16*)(ws + 134217728);            // attn out [2048][4096]
  float* biasv = (float*)(ws + 150994944);
  float* scalev = (float*)(ws + 151019520);

  hipFuncSetAttribute(reinterpret_cast<const void*>(&k_gemm6<128, 384, 0>),
                      hipFuncAttributeMaxDynamicSharedMemorySize, 131072);
  hipFuncSetAttribute(reinterpret_cast<const void*>(&k_gemm6<128, 256, 1>),
                      hipFuncAttributeMaxDynamicSharedMemorySize, 98304);

  k_cast_x_split<<<8192, 256, 0, stream>>>(x, Acat);
  k_prep_w<<<24576, 256, 0, stream>>>(wq, wk, wv, bq, bk, bv, sq, sk, sv,
                                      Wcat, biasv, scalev);

  // fused QKV projection (split-x, K=8192, W k-index wraps at 4096)
  // grid: 16 M-tiles x 16 N-tiles(384) = 256 blocks = exactly 1/CU
  k_gemm6<128, 384, 0><<<256, 512, 131072, stream>>>(
      Acat, Wcat, XH, XL, nullptr, scalev, biasv, nullptr, 6144, 8192, 4095, 4096, 16);

  k_rope<<<20480, 256, 0, stream>>>(XH, XL, cosT, sinT, sp);

  f16* Wo_ = Acat;  // Acat dead after QKV GEMM
  k_cast_i32_f16<<<16384, 256, 0, stream>>>(wo, Wo_, 16777216);

  k_attn2<<<dim3(16, 32, 2), 256, 0, stream>>>(XH, XL, AO);

  // output projection -> f32; 16 x 16 = 256 blocks = exactly 1/CU
  k_gemm6<128, 256, 1><<<256, 512, 98304, stream>>>(
      AO, Wo_, nullptr, nullptr, (float*)d_out, nullptr, nullptr, so, 4096, 4096,
      0x7fffffff, 4096, 16);
}

// Round 8
// 495.403 us; speedup vs baseline: 1.0330x; 1.0330x over previous
//
#include <hip/hip_runtime.h>
#include <hip/hip_bf16.h>
#include <hip/hip_fp16.h>
#include <cstdint>

typedef _Float16 f16;
typedef _Float16 f16x8 __attribute__((ext_vector_type(8)));
typedef _Float16 f16x4 __attribute__((ext_vector_type(4)));
typedef float f32x4 __attribute__((ext_vector_type(4)));

#define DEV_INLINE __device__ __forceinline__

// async 16B/lane global->LDS. LDS dest is wave-uniform base + lane*16.
DEV_INLINE void async_ld16(const void* g, void* l) {
  __builtin_amdgcn_global_load_lds((const __attribute__((address_space(1))) void*)g,
                                   (__attribute__((address_space(3))) void*)l, 16, 0, 0);
}

template <int N>
DEV_INLINE void wait_vm() {
  static_assert(N >= 0 && N <= 12, "gate range");
  if constexpr (N == 0)  asm volatile("s_waitcnt vmcnt(0)" ::: "memory");
  if constexpr (N == 1)  asm volatile("s_waitcnt vmcnt(1)" ::: "memory");
  if constexpr (N == 2)  asm volatile("s_waitcnt vmcnt(2)" ::: "memory");
  if constexpr (N == 3)  asm volatile("s_waitcnt vmcnt(3)" ::: "memory");
  if constexpr (N == 4)  asm volatile("s_waitcnt vmcnt(4)" ::: "memory");
  if constexpr (N == 5)  asm volatile("s_waitcnt vmcnt(5)" ::: "memory");
  if constexpr (N == 6)  asm volatile("s_waitcnt vmcnt(6)" ::: "memory");
  if constexpr (N == 7)  asm volatile("s_waitcnt vmcnt(7)" ::: "memory");
  if constexpr (N == 8)  asm volatile("s_waitcnt vmcnt(8)" ::: "memory");
  if constexpr (N == 9)  asm volatile("s_waitcnt vmcnt(9)" ::: "memory");
  if constexpr (N == 10) asm volatile("s_waitcnt vmcnt(10)" ::: "memory");
  if constexpr (N == 11) asm volatile("s_waitcnt vmcnt(11)" ::: "memory");
  if constexpr (N == 12) asm volatile("s_waitcnt vmcnt(12)" ::: "memory");
}

// counted DS gate: after issuing R new ds_reads, wait_lgk<R>() certifies all
// OLDER ds_reads complete (in-order retirement). sched_barrier stops MFMA hoist
// (rule #18).
template <int N>
DEV_INLINE void wait_lgk() {
  static_assert(N >= 0 && N <= 15, "lgk range");
  if constexpr (N == 0) asm volatile("s_waitcnt lgkmcnt(0)" ::: "memory");
  if constexpr (N == 1) asm volatile("s_waitcnt lgkmcnt(1)" ::: "memory");
  if constexpr (N == 2) asm volatile("s_waitcnt lgkmcnt(2)" ::: "memory");
  if constexpr (N == 3) asm volatile("s_waitcnt lgkmcnt(3)" ::: "memory");
  if constexpr (N == 4) asm volatile("s_waitcnt lgkmcnt(4)" ::: "memory");
  if constexpr (N == 5) asm volatile("s_waitcnt lgkmcnt(5)" ::: "memory");
  if constexpr (N == 6) asm volatile("s_waitcnt lgkmcnt(6)" ::: "memory");
  if constexpr (N == 7) asm volatile("s_waitcnt lgkmcnt(7)" ::: "memory");
  __builtin_amdgcn_sched_barrier(0);
}

// ---------------- elementwise prep kernels ----------------

// x f32 [2048][4096] -> Acat f16 [2048][8192] = [hi(4096) | lo(4096)]
__global__ __launch_bounds__(256) void k_cast_x_split(const float* __restrict__ x,
                                                      f16* __restrict__ acat) {
  int idx = blockIdx.x * 256 + threadIdx.x;
  int i = idx * 4;
  if (i >= 2048 * 4096) return;
  float4 v = *(const float4*)&x[i];
  int row = i >> 12, col = i & 4095;
  f16 h0 = (f16)v.x, h1 = (f16)v.y, h2 = (f16)v.z, h3 = (f16)v.w;
  f16x4 hi = {h0, h1, h2, h3};
  f16x4 lo = {(f16)(v.x - (float)h0), (f16)(v.y - (float)h1),
              (f16)(v.z - (float)h2), (f16)(v.w - (float)h3)};
  size_t base = (size_t)row * 8192 + col;
  *(f16x4*)&acat[base] = hi;
  *(f16x4*)&acat[base + 4096] = lo;
}

// int32 weights (values in [-127,127], exact in f16) -> f16
__global__ __launch_bounds__(256) void k_cast_i32_f16(const int* __restrict__ w,
                                                      f16* __restrict__ out, int n) {
  int i = (blockIdx.x * 256 + threadIdx.x) * 4;
  if (i >= n) return;
  int4 v = *(const int4*)&w[i];
  f16x4 o = {(f16)(float)v.x, (f16)(float)v.y, (f16)(float)v.z, (f16)(float)v.w};
  *(f16x4*)&out[i] = o;
}

// merged: wq|wk|wv -> Wcat f16 [6144][4096] + bias/scale vectors
__global__ __launch_bounds__(256) void k_prep_w(
    const int* __restrict__ wq, const int* __restrict__ wk, const int* __restrict__ wv,
    const float* __restrict__ bq, const float* __restrict__ bk, const float* __restrict__ bv,
    const float* __restrict__ sq, const float* __restrict__ sk, const float* __restrict__ sv,
    f16* __restrict__ wcat, float* __restrict__ bias_cat, float* __restrict__ scale_cat) {
  int i = blockIdx.x * 256 + threadIdx.x;
  if (i < 6291456) {
    int e = i * 4, row = e >> 12, col = e & 4095;
    int4 v;
    if (row < 4096)      v = *(const int4*)&wq[(size_t)row * 4096 + col];
    else if (row < 5120) v = *(const int4*)&wk[(size_t)(row - 4096) * 4096 + col];
    else                 v = *(const int4*)&wv[(size_t)(row - 5120) * 4096 + col];
    f16x4 o = {(f16)(float)v.x, (f16)(float)v.y, (f16)(float)v.z, (f16)(float)v.w};
    *(f16x4*)&wcat[e] = o;
  }
  if (i < 6144) {
    float b, s;
    if (i < 4096)      { b = bq[i];        s = sq[0]; }
    else if (i < 5120) { b = bk[i - 4096]; s = sk[0]; }
    else               { b = bv[i - 5120]; s = sv[0]; }
    bias_cat[i] = b;
    scale_cat[i] = s;
  }
}

// ---------------- GEMM v7: in-wave pipelined reads (counted lgkmcnt), 4-slot ring ----------------
// C[M,N] = A[M,K] * W[N,ldw]^T, k wraps by kmask on the W side.
// 512 threads = 8 waves (2M x 4N). BK=32, 4-slot LDS ring, 2 phases/tile.
// Per tile t (consume reg-set P=t&1):
//   ph0: issue Bhi(t) ds_reads; wait_lgk<NH> (A(t),Blo(t) certified); MFMA-lo;
//        BAR1 (all waves done reading slot t-1 -> overwrite ok);
//        stage(t+3 -> slot (t+3)%4); wait_vm<2*SOPS> (stage(t+1) retired);
//        BAR2 (buf(t+1) visible block-wide);
//   ph1: issue A(t+1),Blo(t+1) into set P^1; wait_lgk<MR+NH> (Bhi(t) certified);
//        MFMA-hi.
// Reads fly under the previous MFMA cluster -> LDS || MFMA overlap in-wave.
// vmcnt never 0 until the drain tiles. Gate->barrier->read invariant everywhere.
template <int BM, int BN, int MODE>
__global__ __launch_bounds__(512) void k_gemm7(
    const f16* __restrict__ A, const f16* __restrict__ W,
    f16* __restrict__ o_hi, f16* __restrict__ o_lo, float* __restrict__ o_f32,
    const float* __restrict__ scale_vec, const float* __restrict__ bias_vec,
    const float* __restrict__ scale_scalar,
    int N, int K, int kmask, int ldw, int nym) {
  constexpr int WM = 2, WN = 4;
  constexpr int MR = BM / WM / 16;      // 4
  constexpr int NR = BN / WN / 16;      // 6 (qkv) / 4 (oproj)
  constexpr int NH = NR / 2;            // 3 / 2
  constexpr int ATB = BM * 64;          // A tile bytes (BK=32: BM rows x 32 f16)
  constexpr int BTB = BN * 64;
  constexpr int SLOT = ATB + BTB;
  constexpr int LA = ATB / 8192;        // glds ops per A tile per thread (1)
  constexpr int LB = BTB / 8192;        // 3 / 2
  constexpr int SOPS = LA + LB;         // 4 / 3
  constexpr int GS = 2 * SOPS;          // steady gate (2 tiles of stages in flight)
  extern __shared__ __align__(16) char lds[];

  const int t = threadIdx.x, w = t >> 6, ln = t & 63;
  const int lr = ln & 15, lg = ln >> 4;
  const int wn = w & 3, wm = w >> 2;

  // T1: bijective XCD swizzle (m204)
  const int nwg = gridDim.x;
  const int q8 = nwg >> 3, r8 = nwg & 7;
  const int xcd = blockIdx.x & 7, bidx = blockIdx.x >> 3;
  const int sid = (xcd < r8 ? xcd * (q8 + 1) : r8 * (q8 + 1) + (xcd - r8) * q8) + bidx;
  const int m0 = (sid % nym) * BM;
  const int n0 = (sid / nym) * BN;

  // per-thread staging sources (global addr carries the chunk swizzle)
  const f16* aSrc[LA];
  const f16* bSrc[LB];
#pragma unroll
  for (int l = 0; l < LA; l++) {
    int ci = l * 512 + t, row = ci >> 2, c = ci & 3;
    aSrc[l] = A + (size_t)(m0 + row) * K + (c ^ ((row >> 1) & 3)) * 8;
  }
#pragma unroll
  for (int l = 0; l < LB; l++) {
    int ci = l * 512 + t, row = ci >> 2, c = ci & 3;
    bSrc[l] = W + (size_t)(n0 + row) * ldw + (c ^ ((row >> 1) & 3)) * 8;
  }

  f32x4 acc[MR][NR] = {};
  f16x8 af0[MR], af1[MR], blo0[NH], blo1[NH], bfhi[NH];

  auto stage = [&](int tt, int slot) {
    char* dst = lds + slot * SLOT;
    const int ko = tt * 32;
    const int kb = ko & kmask;
#pragma unroll
    for (int l = 0; l < LA; l++)
      async_ld16(aSrc[l] + ko, dst + (l * 512 + w * 64) * 16);
#pragma unroll
    for (int l = 0; l < LB; l++)
      async_ld16(bSrc[l] + kb, dst + ATB + (l * 512 + w * 64) * 16);
  };
  auto readANlo = [&](f16x8 (&af)[MR], f16x8 (&blo)[NH], int slot) {
    const char* base = lds + slot * SLOT;
#pragma unroll
    for (int mf = 0; mf < MR; mf++) {
      const int row = wm * (BM / WM) + mf * 16 + lr;
      af[mf] = *(const f16x8*)(base + row * 64 + (lg ^ ((row >> 1) & 3)) * 16);
    }
    const char* bb = base + ATB;
#pragma unroll
    for (int nf = 0; nf < NH; nf++) {
      const int row = wn * (BN / WN) + nf * 16 + lr;
      blo[nf] = *(const f16x8*)(bb + row * 64 + (lg ^ ((row >> 1) & 3)) * 16);
    }
  };
  auto readBhi = [&](int slot) {
    const char* bb = lds + slot * SLOT + ATB;
#pragma unroll
    for (int nf = 0; nf < NH; nf++) {
      const int row = wn * (BN / WN) + (NH + nf) * 16 + lr;
      bfhi[nf] = *(const f16x8*)(bb + row * 64 + (lg ^ ((row >> 1) & 3)) * 16);
    }
  };
  auto mma_lo = [&](f16x8 (&af)[MR], f16x8 (&blo)[NH]) {
    __builtin_amdgcn_s_setprio(1);
#pragma unroll
    for (int m = 0; m < MR; m++)
#pragma unroll
      for (int n = 0; n < NH; n++)
        acc[m][n] = __builtin_amdgcn_mfma_f32_16x16x32_f16(af[m], blo[n], acc[m][n], 0, 0, 0);
    __builtin_amdgcn_s_setprio(0);
  };
  auto mma_hi = [&](f16x8 (&af)[MR]) {
    __builtin_amdgcn_s_setprio(1);
#pragma unroll
    for (int m = 0; m < MR; m++)
#pragma unroll
      for (int n = 0; n < NH; n++)
        acc[m][NH + n] =
            __builtin_amdgcn_mfma_f32_16x16x32_f16(af[m], bfhi[n], acc[m][NH + n], 0, 0, 0);
    __builtin_amdgcn_s_setprio(0);
  };
  auto bar = [&]() { __builtin_amdgcn_s_barrier(); };

  const int NT = K >> 5;  // BK=32; NT even for all our shapes
  int sc = 0, sn = 1, s3 = 3;
  auto rot = [&]() { int tmp = sc; sc = sn; sn = (sn + 1) & 3; s3 = tmp; };
  // slot of tile tt = tt%4; stage target (tt+3)%4. Track sc=tt%4, sn=(tt+1)%4,
  // s3=(tt+3)%4; rotation per tile: sc<-sn, sn<-sn+1, s3<-old sc.

  // prologue: stage tiles 0,1,2 into slots 0,1,2; certify tile0; first reads
  stage(0, 0); stage(1, 1); stage(2, 2);
  wait_vm<GS>();  // stage(0) retired (stages 1,2 = 2*SOPS outstanding)
  bar();
  readANlo(af0, blo0, 0);

  auto tile_full = [&](f16x8 (&afC)[MR], f16x8 (&bloC)[NH],
                       f16x8 (&afN)[MR], f16x8 (&bloN)[NH], int tt) {
    readBhi(sc);
    wait_lgk<NH>();       // A(t),Blo(t) certified
    mma_lo(afC, bloC);
    bar();                // BAR1: slot (t-1) reads done block-wide
    stage(tt + 3, s3);
    wait_vm<GS>();        // stage(t+1) retired
    bar();                // BAR2: buf(t+1) visible
    readANlo(afN, bloN, sn);
    wait_lgk<MR + NH>();  // Bhi(t) certified
    mma_hi(afC);
    rot();
  };

  for (int tt = 0; tt + 5 < NT; tt += 2) {
    tile_full(af0, blo0, af1, blo1, tt);
    tile_full(af1, blo1, af0, blo0, tt + 1);
  }
  // tt = NT-4 (parity 0): last full tile (stages NT-1)
  tile_full(af0, blo0, af1, blo1, NT - 4);
  {  // tt = NT-3 (parity 1): no stage; gate certifies stage(NT-2)
    readBhi(sc);
    wait_lgk<NH>();
    mma_lo(af1, blo1);
    bar();
    wait_vm<SOPS>();      // only stage(NT-1) may remain outstanding
    bar();
    readANlo(af0, blo0, sn);
    wait_lgk<MR + NH>();
    mma_hi(af1);
    rot();
  }
  {  // tt = NT-2 (parity 0): gate certifies stage(NT-1)
    readBhi(sc);
    wait_lgk<NH>();
    mma_lo(af0, blo0);
    bar();
    wait_vm<0>();
    bar();
    readANlo(af1, blo1, sn);
    wait_lgk<MR + NH>();
    mma_hi(af0);
    rot();
  }
  {  // tt = NT-1 (parity 1): final
    readBhi(sc);
    wait_lgk<NH>();
    mma_lo(af1, blo1);
    wait_lgk<0>();
    mma_hi(af1);
  }

#pragma unroll
  for (int n = 0; n < NR; n++) {
    const int col = n0 + wn * (BN / WN) + n * 16 + lr;
    const float sc2 = (MODE == 0) ? scale_vec[col] : scale_scalar[0];
    const float bs = (MODE == 0) ? bias_vec[col] : 0.f;
#pragma unroll
    for (int m = 0; m < MR; m++)
#pragma unroll
      for (int r2 = 0; r2 < 4; r2++) {
        const int row = m0 + wm * (BM / WM) + m * 16 + lg * 4 + r2;
        const float v = acc[m][n][r2] * sc2 + bs;
        if constexpr (MODE == 0) {
          f16 h = (f16)v;
          o_hi[(size_t)row * N + col] = h;
          o_lo[(size_t)row * N + col] = (f16)(v - (float)h);
        } else {
          o_f32[(size_t)row * N + col] = v;
        }
      }
  }
}

// ---------------- RoPE on split Q/K (cols 0..5119 of 6144), f32 math ----------------
__global__ __launch_bounds__(256) void k_rope(f16* __restrict__ XH, f16* __restrict__ XL,
                                              const float* __restrict__ cosT,
                                              const float* __restrict__ sinT,
                                              const int* __restrict__ sp) {
  int idx = blockIdx.x * 256 + threadIdx.x;  // 2048 tokens * 40 heads * 64 pairs
  if (idx >= 2048 * 40 * 64) return;
  int p = idx & 63;
  int hh = (idx >> 6) % 40;
  int tkn = idx / (40 * 64);
  int col = (hh < 32) ? hh * 128 + p : 4096 + (hh - 32) * 128 + p;
  size_t i1 = (size_t)tkn * 6144 + col, i2 = i1 + 64;
  float x1 = (float)XH[i1] + (float)XL[i1];
  float x2 = (float)XH[i2] + (float)XL[i2];
  int pos = (tkn & 1023) + sp[0];
  float c = cosT[pos * 128 + p], s = sinT[pos * 128 + p];
  float o1 = x1 * c - x2 * s;
  float o2 = x2 * c + x1 * s;
  f16 h1 = (f16)o1, h2 = (f16)o2;
  XH[i1] = h1; XL[i1] = (f16)(o1 - (float)h1);
  XH[i2] = h2; XL[i2] = (f16)(o2 - (float)h2);
}

// ---------------- flash attention, causal, GQA 4:1 (round-6 version, reverted) ----------------
__global__ __launch_bounds__(256) void k_attn(const f16* __restrict__ XH,
                                              const f16* __restrict__ XL,
                                              f16* __restrict__ out) {
  __shared__ __align__(16) f16 KsH[32 * 152];
  __shared__ __align__(16) f16 KsL[32 * 152];
  __shared__ __align__(16) f16 VT[128 * 40];
  __shared__ __align__(16) f16 Pb[4 * 16 * 40];
  const int t = threadIdx.x, w = t >> 6, l = t & 63;
  const int lr = l & 15, lg = l >> 4;
  const int qb = blockIdx.x, h = blockIdx.y, b = blockIdx.z;
  const int q0 = qb * 64, kvh = h >> 2;
  const size_t rs_ = 6144;
  const f16* Qh = XH + ((size_t)(b * 1024 + q0)) * rs_ + h * 128;
  const f16* Ql_ = XL + ((size_t)(b * 1024 + q0)) * rs_ + h * 128;
  const f16* KhG = XH + ((size_t)(b * 1024)) * rs_ + 4096 + kvh * 128;
  const f16* KlG = XL + ((size_t)(b * 1024)) * rs_ + 4096 + kvh * 128;
  const f16* VG = XH + ((size_t)(b * 1024)) * rs_ + 5120 + kvh * 128;

  f16x8 qh[4], ql[4];
  {
    size_t qoff = (size_t)(w * 16 + lr) * rs_ + lg * 8;
#pragma unroll
    for (int c = 0; c < 4; c++) {
      qh[c] = *(const f16x8*)(Qh + qoff + c * 32);
      ql[c] = *(const f16x8*)(Ql_ + qoff + c * 32);
    }
  }
  f32x4 accd[8] = {};
  float m_r[4], l_r[4];
#pragma unroll
  for (int r = 0; r < 4; r++) { m_r[r] = -1e30f; l_r[r] = 0.f; }

  const int nkv = q0 + 64;
  for (int kv0 = 0; kv0 < nkv; kv0 += 32) {
    __syncthreads();
#pragma unroll
    for (int i = 0; i < 2; i++) {
      int slot = i * 256 + t, row = slot >> 4, ch = slot & 15;
      size_t go = (size_t)(kv0 + row) * rs_ + ch * 8;
      *(f16x8*)&KsH[row * 152 + ch * 8] = *(const f16x8*)(KhG + go);
      *(f16x8*)&KsL[row * 152 + ch * 8] = *(const f16x8*)(KlG + go);
    }
#pragma unroll
    for (int i = 0; i < 2; i++) {
      int slot = i * 256 + t, row = slot & 31, d8 = slot >> 5;
      f16x8 vv = *(const f16x8*)(VG + (size_t)(kv0 + row) * rs_ + d8 * 8);
#pragma unroll
      for (int j = 0; j < 8; j++) VT[(d8 * 8 + j) * 40 + row] = vv[j];
    }
    __syncthreads();

    f32x4 sc[2] = {};
#pragma unroll
    for (int cb = 0; cb < 2; cb++)
#pragma unroll
      for (int c = 0; c < 4; c++) {
        const f16x8 kh = *(const f16x8*)&KsH[(cb * 16 + lr) * 152 + c * 32 + lg * 8];
        const f16x8 kl = *(const f16x8*)&KsL[(cb * 16 + lr) * 152 + c * 32 + lg * 8];
        sc[cb] = __builtin_amdgcn_mfma_f32_16x16x32_f16(qh[c], kh, sc[cb], 0, 0, 0);
        sc[cb] = __builtin_amdgcn_mfma_f32_16x16x32_f16(qh[c], kl, sc[cb], 0, 0, 0);
        sc[cb] = __builtin_amdgcn_mfma_f32_16x16x32_f16(ql[c], kh, sc[cb], 0, 0, 0);
      }

    const float scale = 0.088388347648318447f;
    float alpha[4], pv[2][4];
#pragma unroll
    for (int r = 0; r < 4; r++) {
      const int qg = q0 + w * 16 + lg * 4 + r;
      float mx = -1e30f;
#pragma unroll
      for (int cb = 0; cb < 2; cb++) {
        const int kg = kv0 + cb * 16 + lr;
        float s = sc[cb][r] * scale;
        s = (kg <= qg) ? s : -1e30f;
        pv[cb][r] = s;
        mx = fmaxf(mx, s);
      }
      mx = fmaxf(mx, __shfl_xor(mx, 1));
      mx = fmaxf(mx, __shfl_xor(mx, 2));
      mx = fmaxf(mx, __shfl_xor(mx, 4));
      mx = fmaxf(mx, __shfl_xor(mx, 8));
      const float mn = fmaxf(m_r[r], mx);
      alpha[r] = __expf(m_r[r] - mn);
      m_r[r] = mn;
      float rsum = 0.f;
#pragma unroll
      for (int cb = 0; cb < 2; cb++) {
        const int kg = kv0 + cb * 16 + lr;
        const float p = (kg <= qg) ? __expf(pv[cb][r] - mn) : 0.f;
        pv[cb][r] = p;
        rsum += p;
      }
      rsum += __shfl_xor(rsum, 1);
      rsum += __shfl_xor(rsum, 2);
      rsum += __shfl_xor(rsum, 4);
      rsum += __shfl_xor(rsum, 8);
      l_r[r] = l_r[r] * alpha[r] + rsum;
    }

    f16* Pw = &Pb[w * 16 * 40];
#pragma unroll
    for (int r = 0; r < 4; r++)
#pragma unroll
      for (int cb = 0; cb < 2; cb++)
        Pw[(lg * 4 + r) * 40 + cb * 16 + lr] = (f16)pv[cb][r];
    const f16x8 pf = *(const f16x8*)&Pw[lr * 40 + lg * 8];

#pragma unroll
    for (int dc = 0; dc < 8; dc++) {
      const f16x8 vf = *(const f16x8*)&VT[(dc * 16 + lr) * 40 + lg * 8];
#pragma unroll
      for (int r = 0; r < 4; r++) accd[dc][r] *= alpha[r];
      accd[dc] = __builtin_amdgcn_mfma_f32_16x16x32_f16(pf, vf, accd[dc], 0, 0, 0);
    }
  }

#pragma unroll
  for (int dc = 0; dc < 8; dc++)
#pragma unroll
    for (int r = 0; r < 4; r++) {
      const int row = b * 1024 + q0 + w * 16 + lg * 4 + r;
      out[(size_t)row * 4096 + h * 128 + dc * 16 + lr] = (f16)(accd[dc][r] / l_r[r]);
    }
}

// ---------------- launch ----------------
extern "C" void kernel_launch(void* const* d_in, const int* in_sizes, int n_in,
                              void* d_out, int out_size, void* d_ws, size_t ws_size,
                              hipStream_t stream) {
  const float* x = (const float*)d_in[0];
  const float* cosT = (const float*)d_in[2];
  const float* sinT = (const float*)d_in[3];
  const int* wq = (const int*)d_in[4];
  const float* bq = (const float*)d_in[5];
  const float* sq = (const float*)d_in[6];
  const int* wk = (const int*)d_in[7];
  const float* bk = (const float*)d_in[8];
  const float* sk = (const float*)d_in[9];
  const int* wv = (const int*)d_in[10];
  const float* bv = (const float*)d_in[11];
  const float* sv = (const float*)d_in[12];
  const int* wo = (const int*)d_in[13];
  const float* so = (const float*)d_in[14];
  const int* sp = (const int*)d_in[15];

  char* ws = (char*)d_ws;
  f16* Acat = (f16*)ws;                        // x hi|lo [2048][8192]; later reused for Wo
  f16* Wcat = (f16*)(ws + 33554432);           // wq|wk|wv f16 [6144][4096]
  f16* XH = (f16*)(ws + 83886080);             // qkv hi [2048][6144]
  f16* XL = (f16*)(ws + 109051904);            // qkv lo
  f16* AO = (f16*)(ws + 134217728);            // attn out [2048][4096]
  float* biasv = (float*)(ws + 150994944);
  float* scalev = (float*)(ws + 151019520);

  hipFuncSetAttribute(reinterpret_cast<const void*>(&k_gemm7<128, 384, 0>),
                      hipFuncAttributeMaxDynamicSharedMemorySize, 131072);
  hipFuncSetAttribute(reinterpret_cast<const void*>(&k_gemm7<128, 256, 1>),
                      hipFuncAttributeMaxDynamicSharedMemorySize, 98304);

  k_cast_x_split<<<8192, 256, 0, stream>>>(x, Acat);
  k_prep_w<<<24576, 256, 0, stream>>>(wq, wk, wv, bq, bk, bv, sq, sk, sv,
                                      Wcat, biasv, scalev);

  // fused QKV projection (split-x, K=8192, W k-index wraps at 4096)
  // grid: 16 M-tiles x 16 N-tiles(384) = 256 blocks = exactly 1/CU
  k_gemm7<128, 384, 0><<<256, 512, 131072, stream>>>(
      Acat, Wcat, XH, XL, nullptr, scalev, biasv, nullptr, 6144, 8192, 4095, 4096, 16);

  k_rope<<<20480, 256, 0, stream>>>(XH, XL, cosT, sinT, sp);

  f16* Wo_ = Acat;  // Acat dead after QKV GEMM
  k_cast_i32_f16<<<16384, 256, 0, stream>>>(wo, Wo_, 16777216);

  k_attn<<<dim3(16, 32, 2), 256, 0, stream>>>(XH, XL, AO);

  // output projection -> f32; 16 x 16 = 256 blocks = exactly 1/CU
  k_gemm7<128, 256, 1><<<256, 512, 98304, stream>>>(
      AO, Wo_, nullptr, nullptr, (float*)d_out, nullptr, nullptr, so, 4096, 4096,
      0x7fffffff, 4096, 16);
}

// Round 9
// 476.949 us; speedup vs baseline: 1.0730x; 1.0387x over previous
//
#include <hip/hip_runtime.h>
#include <hip/hip_bf16.h>
#include <hip/hip_fp16.h>
#include <cstdint>

typedef _Float16 f16;
typedef _Float16 f16x8 __attribute__((ext_vector_type(8)));
typedef _Float16 f16x4 __attribute__((ext_vector_type(4)));
typedef float f32x4 __attribute__((ext_vector_type(4)));

#define DEV_INLINE __device__ __forceinline__

// async 16B/lane global->LDS. LDS dest is wave-uniform base + lane*16.
DEV_INLINE void async_ld16(const void* g, void* l) {
  __builtin_amdgcn_global_load_lds((const __attribute__((address_space(1))) void*)g,
                                   (__attribute__((address_space(3))) void*)l, 16, 0, 0);
}

template <int N>
DEV_INLINE void wait_vm() {
  static_assert(N >= 0 && N <= 12, "gate range");
  if constexpr (N == 0)  asm volatile("s_waitcnt vmcnt(0)" ::: "memory");
  if constexpr (N == 1)  asm volatile("s_waitcnt vmcnt(1)" ::: "memory");
  if constexpr (N == 2)  asm volatile("s_waitcnt vmcnt(2)" ::: "memory");
  if constexpr (N == 3)  asm volatile("s_waitcnt vmcnt(3)" ::: "memory");
  if constexpr (N == 4)  asm volatile("s_waitcnt vmcnt(4)" ::: "memory");
  if constexpr (N == 5)  asm volatile("s_waitcnt vmcnt(5)" ::: "memory");
  if constexpr (N == 6)  asm volatile("s_waitcnt vmcnt(6)" ::: "memory");
  if constexpr (N == 7)  asm volatile("s_waitcnt vmcnt(7)" ::: "memory");
  if constexpr (N == 8)  asm volatile("s_waitcnt vmcnt(8)" ::: "memory");
  if constexpr (N == 9)  asm volatile("s_waitcnt vmcnt(9)" ::: "memory");
  if constexpr (N == 10) asm volatile("s_waitcnt vmcnt(10)" ::: "memory");
  if constexpr (N == 11) asm volatile("s_waitcnt vmcnt(11)" ::: "memory");
  if constexpr (N == 12) asm volatile("s_waitcnt vmcnt(12)" ::: "memory");
}
DEV_INLINE void lgk0() {
  asm volatile("s_waitcnt lgkmcnt(0)" ::: "memory");
  __builtin_amdgcn_sched_barrier(0);
}

// ---------------- elementwise prep kernels ----------------

// x f32 [2048][4096] -> Acat f16 [2048][8192] = [hi(4096) | lo(4096)]
__global__ __launch_bounds__(256) void k_cast_x_split(const float* __restrict__ x,
                                                      f16* __restrict__ acat) {
  int idx = blockIdx.x * 256 + threadIdx.x;
  int i = idx * 4;
  if (i >= 2048 * 4096) return;
  float4 v = *(const float4*)&x[i];
  int row = i >> 12, col = i & 4095;
  f16 h0 = (f16)v.x, h1 = (f16)v.y, h2 = (f16)v.z, h3 = (f16)v.w;
  f16x4 hi = {h0, h1, h2, h3};
  f16x4 lo = {(f16)(v.x - (float)h0), (f16)(v.y - (float)h1),
              (f16)(v.z - (float)h2), (f16)(v.w - (float)h3)};
  size_t base = (size_t)row * 8192 + col;
  *(f16x4*)&acat[base] = hi;
  *(f16x4*)&acat[base + 4096] = lo;
}

// int32 weights (values in [-127,127], exact in f16) -> f16
__global__ __launch_bounds__(256) void k_cast_i32_f16(const int* __restrict__ w,
                                                      f16* __restrict__ out, int n) {
  int i = (blockIdx.x * 256 + threadIdx.x) * 4;
  if (i >= n) return;
  int4 v = *(const int4*)&w[i];
  f16x4 o = {(f16)(float)v.x, (f16)(float)v.y, (f16)(float)v.z, (f16)(float)v.w};
  *(f16x4*)&out[i] = o;
}

// merged: wq|wk|wv -> Wcat f16 [6144][4096] + bias/scale vectors
__global__ __launch_bounds__(256) void k_prep_w(
    const int* __restrict__ wq, const int* __restrict__ wk, const int* __restrict__ wv,
    const float* __restrict__ bq, const float* __restrict__ bk, const float* __restrict__ bv,
    const float* __restrict__ sq, const float* __restrict__ sk, const float* __restrict__ sv,
    f16* __restrict__ wcat, float* __restrict__ bias_cat, float* __restrict__ scale_cat) {
  int i = blockIdx.x * 256 + threadIdx.x;
  if (i < 6291456) {
    int e = i * 4, row = e >> 12, col = e & 4095;
    int4 v;
    if (row < 4096)      v = *(const int4*)&wq[(size_t)row * 4096 + col];
    else if (row < 5120) v = *(const int4*)&wk[(size_t)(row - 4096) * 4096 + col];
    else                 v = *(const int4*)&wv[(size_t)(row - 5120) * 4096 + col];
    f16x4 o = {(f16)(float)v.x, (f16)(float)v.y, (f16)(float)v.z, (f16)(float)v.w};
    *(f16x4*)&wcat[e] = o;
  }
  if (i < 6144) {
    float b, s;
    if (i < 4096)      { b = bq[i];        s = sq[0]; }
    else if (i < 5120) { b = bk[i - 4096]; s = sk[0]; }
    else               { b = bv[i - 5120]; s = sv[0]; }
    bias_cat[i] = b;
    scale_cat[i] = s;
  }
}

// ---------------- GEMM v6 (round-6 version, reverted): 8-wave exact-fill, 4-phase ----------------
template <int BM, int BN, int MODE>
__global__ __launch_bounds__(512) void k_gemm6(
    const f16* __restrict__ A, const f16* __restrict__ W,
    f16* __restrict__ o_hi, f16* __restrict__ o_lo, float* __restrict__ o_f32,
    const float* __restrict__ scale_vec, const float* __restrict__ bias_vec,
    const float* __restrict__ scale_scalar,
    int N, int K, int kmask, int ldw, int nym) {
  constexpr int WM = 2, WN = 4;
  constexpr int MR = BM / WM / 16;
  constexpr int NR = BN / WN / 16;
  constexpr int NH = NR / 2;
  constexpr int AKC = BM * 64;
  constexpr int BKC = BN * 64;
  constexpr int SLOT = 2 * (AKC + BKC);
  constexpr int LAH = AKC / 8192;
  constexpr int LBH = BKC / 8192;
  constexpr int GS = 2 * LBH + 3;
  constexpr int GT1 = 2 * LBH + 2;
  constexpr int GT2 = LBH + 1;
  extern __shared__ __align__(16) char lds[];

  const int t = threadIdx.x, w = t >> 6, ln = t & 63;
  const int lr = ln & 15, lg = ln >> 4;
  const int wn = w & 3, wm = w >> 2;

  const int nwg = gridDim.x;
  const int q8 = nwg >> 3, r8 = nwg & 7;
  const int xcd = blockIdx.x & 7, bidx = blockIdx.x >> 3;
  const int sid = (xcd < r8 ? xcd * (q8 + 1) : r8 * (q8 + 1) + (xcd - r8) * q8) + bidx;
  const int m0 = (sid % nym) * BM;
  const int n0 = (sid / nym) * BN;

  const f16* aSrc[LAH];
  const f16* bSrc[LBH];
#pragma unroll
  for (int l = 0; l < LAH; l++) {
    int ci = l * 512 + t, row = ci >> 2, c = ci & 3;
    aSrc[l] = A + (size_t)(m0 + row) * K + (c ^ ((row >> 1) & 3)) * 8;
  }
#pragma unroll
  for (int l = 0; l < LBH; l++) {
    int ci = l * 512 + t, row = ci >> 2, c = ci & 3;
    bSrc[l] = W + (size_t)(n0 + row) * ldw + (c ^ ((row >> 1) & 3)) * 8;
  }

  f32x4 acc[MR][NR] = {};
  f16x8 af[MR], bflo[NH], bfhi[NH];

  auto stageA = [&](int tt, int kc) {
    char* dst = lds + (tt & 1) * SLOT + kc * AKC;
    const int ko = tt * 64 + kc * 32;
#pragma unroll
    for (int l = 0; l < LAH; l++)
      async_ld16(aSrc[l] + ko, dst + (l * 512 + w * 64) * 16);
  };
  auto stageB = [&](int tt, int kc) {
    char* dst = lds + (tt & 1) * SLOT + 2 * AKC + kc * BKC;
    const int ko = ((tt * 64) & kmask) + kc * 32;
#pragma unroll
    for (int l = 0; l < LBH; l++)
      async_ld16(bSrc[l] + ko, dst + (l * 512 + w * 64) * 16);
  };
  auto readA = [&](int tt, int kc) {
    const char* base = lds + (tt & 1) * SLOT + kc * AKC;
#pragma unroll
    for (int mf = 0; mf < MR; mf++) {
      const int row = wm * (BM / WM) + mf * 16 + lr;
      af[mf] = *(const f16x8*)(base + row * 64 + (lg ^ ((row >> 1) & 3)) * 16);
    }
  };
  auto readB = [&](f16x8 (&dst)[NH], int tt, int nq, int kc) {
    const char* base = lds + (tt & 1) * SLOT + 2 * AKC + kc * BKC;
#pragma unroll
    for (int nf = 0; nf < NH; nf++) {
      const int row = wn * (BN / WN) + (nq * NH + nf) * 16 + lr;
      dst[nf] = *(const f16x8*)(base + row * 64 + (lg ^ ((row >> 1) & 3)) * 16);
    }
  };
  auto mma = [&](f16x8 (&b)[NH], int nq) {
    __builtin_amdgcn_s_setprio(1);
#pragma unroll
    for (int m = 0; m < MR; m++)
#pragma unroll
      for (int n = 0; n < NH; n++)
        acc[m][nq * NH + n] =
            __builtin_amdgcn_mfma_f32_16x16x32_f16(af[m], b[n], acc[m][nq * NH + n], 0, 0, 0);
    __builtin_amdgcn_s_setprio(0);
  };
  auto bar = [&]() { __builtin_amdgcn_s_barrier(); };

  const int NT = K >> 6;
  stageA(0, 0); stageB(0, 0); stageA(0, 1); stageB(0, 1);
  stageA(1, 0); stageB(1, 0); stageA(1, 1);
  wait_vm<GS>();
  bar();

  for (int tt = 0; tt + 2 < NT; ++tt) {
    stageB(tt + 1, 1);
    readA(tt, 0); readB(bflo, tt, 0, 0);
    bar(); lgk0(); mma(bflo, 0); bar();
    stageA(tt + 2, 0);
    readB(bfhi, tt, 1, 0);
    wait_vm<GS>();
    bar(); lgk0(); mma(bfhi, 1); bar();
    stageB(tt + 2, 0);
    readA(tt, 1); readB(bflo, tt, 0, 1);
    bar(); lgk0(); mma(bflo, 0); bar();
    stageA(tt + 2, 1);
    readB(bfhi, tt, 1, 1);
    wait_vm<GS>();
    bar(); lgk0(); mma(bfhi, 1); bar();
  }
  {
    const int tt = NT - 2;
    stageB(tt + 1, 1);
    readA(tt, 0); readB(bflo, tt, 0, 0);
    bar(); lgk0(); mma(bflo, 0); bar();
    readB(bfhi, tt, 1, 0);
    wait_vm<GT1>();
    bar(); lgk0(); mma(bfhi, 1); bar();
    readA(tt, 1); readB(bflo, tt, 0, 1);
    bar(); lgk0(); mma(bflo, 0); bar();
    readB(bfhi, tt, 1, 1);
    wait_vm<GT2>();
    bar(); lgk0(); mma(bfhi, 1); bar();
  }
  {
    const int tt = NT - 1;
    readA(tt, 0); readB(bflo, tt, 0, 0);
    bar(); lgk0(); mma(bflo, 0); bar();
    readB(bfhi, tt, 1, 0);
    wait_vm<0>();
    bar(); lgk0(); mma(bfhi, 1); bar();
    readA(tt, 1); readB(bflo, tt, 0, 1);
    bar(); lgk0(); mma(bflo, 0); bar();
    readB(bfhi, tt, 1, 1);
    bar(); lgk0(); mma(bfhi, 1);
  }

#pragma unroll
  for (int n = 0; n < NR; n++) {
    const int col = n0 + wn * (BN / WN) + n * 16 + lr;
    const float sc = (MODE == 0) ? scale_vec[col] : scale_scalar[0];
    const float bs = (MODE == 0) ? bias_vec[col] : 0.f;
#pragma unroll
    for (int m = 0; m < MR; m++)
#pragma unroll
      for (int r2 = 0; r2 < 4; r2++) {
        const int row = m0 + wm * (BM / WM) + m * 16 + lg * 4 + r2;
        const float v = acc[m][n][r2] * sc + bs;
        if constexpr (MODE == 0) {
          f16 h = (f16)v;
          o_hi[(size_t)row * N + col] = h;
          o_lo[(size_t)row * N + col] = (f16)(v - (float)h);
        } else {
          o_f32[(size_t)row * N + col] = v;
        }
      }
  }
}

// ---------------- RoPE on split Q/K (cols 0..5119 of 6144), f32 math ----------------
__global__ __launch_bounds__(256) void k_rope(f16* __restrict__ XH, f16* __restrict__ XL,
                                              const float* __restrict__ cosT,
                                              const float* __restrict__ sinT,
                                              const int* __restrict__ sp) {
  int idx = blockIdx.x * 256 + threadIdx.x;  // 2048 tokens * 40 heads * 64 pairs
  if (idx >= 2048 * 40 * 64) return;
  int p = idx & 63;
  int hh = (idx >> 6) % 40;
  int tkn = idx / (40 * 64);
  int col = (hh < 32) ? hh * 128 + p : 4096 + (hh - 32) * 128 + p;
  size_t i1 = (size_t)tkn * 6144 + col, i2 = i1 + 64;
  float x1 = (float)XH[i1] + (float)XL[i1];
  float x2 = (float)XH[i2] + (float)XL[i2];
  int pos = (tkn & 1023) + sp[0];
  float c = cosT[pos * 128 + p], s = sinT[pos * 128 + p];
  float o1 = x1 * c - x2 * s;
  float o2 = x2 * c + x1 * s;
  f16 h1 = (f16)o1, h2 = (f16)o2;
  XH[i1] = h1; XL[i1] = (f16)(o1 - (float)h1);
  XH[i2] = h2; XL[i2] = (f16)(o2 - (float)h2);
}

// ---------------- flash attention v3: QBLK=128, 8 waves, kvh-pinned XCD swizzle ----------------
// 1D grid 512: id = j*8 + kvh -> all blocks sharing a K/V stream land on XCD kvh
// (round-robin dispatch), so K/V re-reads hit that XCD's L2 (1.5MB << 4MB).
// Per-block q rows = 128 (wave w owns rows q0+16w..+16). Same math as round 6.
__global__ __launch_bounds__(512) void k_attn3(const f16* __restrict__ XH,
                                               const f16* __restrict__ XL,
                                               f16* __restrict__ out) {
  __shared__ __align__(16) f16 KsH[32 * 152];
  __shared__ __align__(16) f16 KsL[32 * 152];
  __shared__ __align__(16) f16 VT[128 * 40];
  __shared__ __align__(16) f16 Pb[8 * 16 * 40];
  const int t = threadIdx.x, w = t >> 6, l = t & 63;
  const int lr = l & 15, lg = l >> 4;
  // decode swizzled block id: id = ((b*4 + hg)*8 + qb)*8 + kvh
  const int id = blockIdx.x;
  const int kvh = id & 7;
  const int j = id >> 3;
  const int qb = j & 7;
  const int hg = (j >> 3) & 3;
  const int b = j >> 5;
  const int h = kvh * 4 + hg;
  const int q0 = qb * 128;
  const size_t rs_ = 6144;
  const f16* Qh = XH + ((size_t)(b * 1024 + q0)) * rs_ + h * 128;
  const f16* Ql_ = XL + ((size_t)(b * 1024 + q0)) * rs_ + h * 128;
  const f16* KhG = XH + ((size_t)(b * 1024)) * rs_ + 4096 + kvh * 128;
  const f16* KlG = XL + ((size_t)(b * 1024)) * rs_ + 4096 + kvh * 128;
  const f16* VG = XH + ((size_t)(b * 1024)) * rs_ + 5120 + kvh * 128;

  f16x8 qh[4], ql[4];
  {
    size_t qoff = (size_t)(w * 16 + lr) * rs_ + lg * 8;
#pragma unroll
    for (int c = 0; c < 4; c++) {
      qh[c] = *(const f16x8*)(Qh + qoff + c * 32);
      ql[c] = *(const f16x8*)(Ql_ + qoff + c * 32);
    }
  }
  f32x4 accd[8] = {};
  float m_r[4], l_r[4];
#pragma unroll
  for (int r = 0; r < 4; r++) { m_r[r] = -1e30f; l_r[r] = 0.f; }

  const int nkv = q0 + 128;
  for (int kv0 = 0; kv0 < nkv; kv0 += 32) {
    __syncthreads();
    {  // stage K hi/lo [32][128] -> padded LDS (512 threads: 1 chunk each)
      int row = t >> 4, ch = t & 15;
      size_t go = (size_t)(kv0 + row) * rs_ + ch * 8;
      *(f16x8*)&KsH[row * 152 + ch * 8] = *(const f16x8*)(KhG + go);
      *(f16x8*)&KsL[row * 152 + ch * 8] = *(const f16x8*)(KlG + go);
    }
    {  // stage V transposed: VT[d][key]
      int row = t & 31, d8 = t >> 5;
      f16x8 vv = *(const f16x8*)(VG + (size_t)(kv0 + row) * rs_ + d8 * 8);
#pragma unroll
      for (int jj = 0; jj < 8; jj++) VT[(d8 * 8 + jj) * 40 + row] = vv[jj];
    }
    __syncthreads();

    f32x4 sc[2] = {};
#pragma unroll
    for (int cb = 0; cb < 2; cb++)
#pragma unroll
      for (int c = 0; c < 4; c++) {
        const f16x8 kh = *(const f16x8*)&KsH[(cb * 16 + lr) * 152 + c * 32 + lg * 8];
        const f16x8 kl = *(const f16x8*)&KsL[(cb * 16 + lr) * 152 + c * 32 + lg * 8];
        sc[cb] = __builtin_amdgcn_mfma_f32_16x16x32_f16(qh[c], kh, sc[cb], 0, 0, 0);
        sc[cb] = __builtin_amdgcn_mfma_f32_16x16x32_f16(qh[c], kl, sc[cb], 0, 0, 0);
        sc[cb] = __builtin_amdgcn_mfma_f32_16x16x32_f16(ql[c], kh, sc[cb], 0, 0, 0);
      }

    const float scale = 0.088388347648318447f;
    float alpha[4], pv[2][4];
#pragma unroll
    for (int r = 0; r < 4; r++) {
      const int qg = q0 + w * 16 + lg * 4 + r;
      float mx = -1e30f;
#pragma unroll
      for (int cb = 0; cb < 2; cb++) {
        const int kg = kv0 + cb * 16 + lr;
        float s = sc[cb][r] * scale;
        s = (kg <= qg) ? s : -1e30f;
        pv[cb][r] = s;
        mx = fmaxf(mx, s);
      }
      mx = fmaxf(mx, __shfl_xor(mx, 1));
      mx = fmaxf(mx, __shfl_xor(mx, 2));
      mx = fmaxf(mx, __shfl_xor(mx, 4));
      mx = fmaxf(mx, __shfl_xor(mx, 8));
      const float mn = fmaxf(m_r[r], mx);
      alpha[r] = __expf(m_r[r] - mn);
      m_r[r] = mn;
      float rsum = 0.f;
#pragma unroll
      for (int cb = 0; cb < 2; cb++) {
        const int kg = kv0 + cb * 16 + lr;
        const float p = (kg <= qg) ? __expf(pv[cb][r] - mn) : 0.f;
        pv[cb][r] = p;
        rsum += p;
      }
      rsum += __shfl_xor(rsum, 1);
      rsum += __shfl_xor(rsum, 2);
      rsum += __shfl_xor(rsum, 4);
      rsum += __shfl_xor(rsum, 8);
      l_r[r] = l_r[r] * alpha[r] + rsum;
    }

    f16* Pw = &Pb[w * 16 * 40];
#pragma unroll
    for (int r = 0; r < 4; r++)
#pragma unroll
      for (int cb = 0; cb < 2; cb++)
        Pw[(lg * 4 + r) * 40 + cb * 16 + lr] = (f16)pv[cb][r];
    const f16x8 pf = *(const f16x8*)&Pw[lr * 40 + lg * 8];

#pragma unroll
    for (int dc = 0; dc < 8; dc++) {
      const f16x8 vf = *(const f16x8*)&VT[(dc * 16 + lr) * 40 + lg * 8];
#pragma unroll
      for (int r = 0; r < 4; r++) accd[dc][r] *= alpha[r];
      accd[dc] = __builtin_amdgcn_mfma_f32_16x16x32_f16(pf, vf, accd[dc], 0, 0, 0);
    }
  }

#pragma unroll
  for (int dc = 0; dc < 8; dc++)
#pragma unroll
    for (int r = 0; r < 4; r++) {
      const int row = b * 1024 + q0 + w * 16 + lg * 4 + r;
      out[(size_t)row * 4096 + h * 128 + dc * 16 + lr] = (f16)(accd[dc][r] / l_r[r]);
    }
}

// ---------------- launch ----------------
extern "C" void kernel_launch(void* const* d_in, const int* in_sizes, int n_in,
                              void* d_out, int out_size, void* d_ws, size_t ws_size,
                              hipStream_t stream) {
  const float* x = (const float*)d_in[0];
  const float* cosT = (const float*)d_in[2];
  const float* sinT = (const float*)d_in[3];
  const int* wq = (const int*)d_in[4];
  const float* bq = (const float*)d_in[5];
  const float* sq = (const float*)d_in[6];
  const int* wk = (const int*)d_in[7];
  const float* bk = (const float*)d_in[8];
  const float* sk = (const float*)d_in[9];
  const int* wv = (const int*)d_in[10];
  const float* bv = (const float*)d_in[11];
  const float* sv = (const float*)d_in[12];
  const int* wo = (const int*)d_in[13];
  const float* so = (const float*)d_in[14];
  const int* sp = (const int*)d_in[15];

  char* ws = (char*)d_ws;
  f16* Acat = (f16*)ws;                        // x hi|lo [2048][8192]; later reused for Wo
  f16* Wcat = (f16*)(ws + 33554432);           // wq|wk|wv f16 [6144][4096]
  f16* XH = (f16*)(ws + 83886080);             // qkv hi [2048][6144]
  f16* XL = (f16*)(ws + 109051904);            // qkv lo
  f16* AO = (f16*)(ws + 134217728);            // attn out [2048][4096]
  float* biasv = (float*)(ws + 150994944);
  float* scalev = (float*)(ws + 151019520);

  hipFuncSetAttribute(reinterpret_cast<const void*>(&k_gemm6<128, 384, 0>),
                      hipFuncAttributeMaxDynamicSharedMemorySize, 131072);
  hipFuncSetAttribute(reinterpret_cast<const void*>(&k_gemm6<128, 256, 1>),
                      hipFuncAttributeMaxDynamicSharedMemorySize, 98304);

  k_cast_x_split<<<8192, 256, 0, stream>>>(x, Acat);
  k_prep_w<<<24576, 256, 0, stream>>>(wq, wk, wv, bq, bk, bv, sq, sk, sv,
                                      Wcat, biasv, scalev);

  // fused QKV projection (split-x, K=8192, W k-index wraps at 4096)
  // grid: 16 M-tiles x 16 N-tiles(384) = 256 blocks = exactly 1/CU
  k_gemm6<128, 384, 0><<<256, 512, 131072, stream>>>(
      Acat, Wcat, XH, XL, nullptr, scalev, biasv, nullptr, 6144, 8192, 4095, 4096, 16);

  k_rope<<<20480, 256, 0, stream>>>(XH, XL, cosT, sinT, sp);

  f16* Wo_ = Acat;  // Acat dead after QKV GEMM
  k_cast_i32_f16<<<16384, 256, 0, stream>>>(wo, Wo_, 16777216);

  // attention: 512 blocks (QBLK=128), kvh-pinned XCD swizzle baked into id decode
  k_attn3<<<512, 512, 0, stream>>>(XH, XL, AO);

  // output projection -> f32; 16 x 16 = 256 blocks = exactly 1/CU
  k_gemm6<128, 256, 1><<<256, 512, 98304, stream>>>(
      AO, Wo_, nullptr, nullptr, (float*)d_out, nullptr, nullptr, so, 4096, 4096,
      0x7fffffff, 4096, 16);
}